// Round 1
// 11543.878 us; speedup vs baseline: 1.0688x; 1.0688x over previous
//
#include <hip/hip_runtime.h>

// Problem constants
#define B_ 128
#define T_ 256
#define F_ 1024
#define H_ 1024

typedef __bf16 bf16x8 __attribute__((ext_vector_type(8)));
typedef __bf16 bf16x4 __attribute__((ext_vector_type(4)));
typedef float f32x4 __attribute__((ext_vector_type(4)));

// LDS weight tile row stride (bf16 elems): 2056*2 = 4112 B.
// 4112 % 128 = 16 -> rows r and r+8 alias banks (2-way conflict = free, m136).
#define WROW 2056

__device__ __forceinline__ float sigf(float v)  { return 1.0f / (1.0f + __expf(-v)); }
// NaN-free tanh
__device__ __forceinline__ float tanhfast(float x) { return 1.0f - 2.0f / (1.0f + __expf(2.0f * x)); }

// fp32 -> bf16 (n must equal 8*256*gridDim)
__global__ void k_cvt(const float* __restrict__ src, __bf16* __restrict__ dst, int n) {
    int i = (blockIdx.x * 256 + threadIdx.x) * 8;
    if (i + 7 < n) {
        float4 a = *(const float4*)(src + i);
        float4 b = *(const float4*)(src + i + 4);
        bf16x8 o = { (__bf16)a.x, (__bf16)a.y, (__bf16)a.z, (__bf16)a.w,
                     (__bf16)b.x, (__bf16)b.y, (__bf16)b.z, (__bf16)b.w };
        *(bf16x8*)(dst + i) = o;
    }
}

// Zero the t=-1 h buffers and the grid-barrier state (ws is poisoned).
__global__ void k_init(__bf16* h0b, __bf16* h1b, unsigned* bar) {
    int i = blockIdx.x * 256 + threadIdx.x;   // 512 x 256 = 131072 exactly
    h0b[i] = (__bf16)0.0f;
    h1b[i] = (__bf16)0.0f;
    if (i < 64) bar[i] = 0u;
}

// Sense-reversing grid barrier (256 blocks). Agent-scope atomics + threadfence
// give cross-XCD visibility of the h writes (buffer_wbl2 / buffer_inv).
__device__ __forceinline__ void grid_barrier(unsigned* cnt, unsigned* gen) {
    __syncthreads();                      // drains all waves' vmcnt (s_barrier semantics)
    if (threadIdx.x == 0) {
        __threadfence();                  // release: flush this XCD's L2 to coherence point
        unsigned g = __hip_atomic_load(gen, __ATOMIC_RELAXED, __HIP_MEMORY_SCOPE_AGENT);
        unsigned a = __hip_atomic_fetch_add(cnt, 1u, __ATOMIC_ACQ_REL, __HIP_MEMORY_SCOPE_AGENT);
        if (a == 255u) {
            __hip_atomic_store(cnt, 0u, __ATOMIC_RELAXED, __HIP_MEMORY_SCOPE_AGENT);
            __hip_atomic_store(gen, g + 1u, __ATOMIC_RELEASE, __HIP_MEMORY_SCOPE_AGENT);
        } else {
            while (__hip_atomic_load(gen, __ATOMIC_ACQUIRE, __HIP_MEMORY_SCOPE_AGENT) == g)
                __builtin_amdgcn_s_sleep(4);
        }
        __threadfence();                  // acquire: invalidate stale L1/L2 lines
    }
    __syncthreads();
}

// 4 MFMAs of one K=32 slice: 2 M-tiles x 2 N-tiles, B from resident LDS weights.
#define MFMA4(A0, A1, KOFF) do { \
    bf16x8 b0_ = *(const bf16x8*)&wB[lrow][(KOFF) + quad * 8]; \
    bf16x8 b1_ = *(const bf16x8*)&wB[16 + lrow][(KOFF) + quad * 8]; \
    acc00 = __builtin_amdgcn_mfma_f32_16x16x32_bf16(A0, b0_, acc00, 0, 0, 0); \
    acc01 = __builtin_amdgcn_mfma_f32_16x16x32_bf16(A0, b1_, acc01, 0, 0, 0); \
    acc10 = __builtin_amdgcn_mfma_f32_16x16x32_bf16(A1, b0_, acc10, 0, 0, 0); \
    acc11 = __builtin_amdgcn_mfma_f32_16x16x32_bf16(A1, b1_, acc11, 0, 0, 0); \
} while (0)

// Epilogue for one M-tile: lanes jj / jj+8 hold (i,g) / (f,o) for column j0+jj;
// one shfl_xor(8) pair reunites the 4 gates. Only lanes with bit3==0 store.
#define EPI(MT, ACC_A, ACC_B) \
    _Pragma("unroll") \
    for (int r = 0; r < 4; ++r) { \
        float v0 = (ACC_A)[r], v1 = (ACC_B)[r]; \
        float q0 = __shfl_xor(v0, 8); \
        float q1 = __shfl_xor(v1, 8); \
        float iv = (hi ? q0 : v0) + bi; \
        float fv = (hi ? v0 : q0) + bf_; \
        float gv = (hi ? q1 : v1) + bg; \
        float ov = (hi ? v1 : q1) + bo; \
        float cn = sigf(fv) * creg[MT][r] + sigf(iv) * tanhfast(gv); \
        creg[MT][r] = cn; \
        float hn = sigf(ov) * tanhfast(cn); \
        if (!hi) { \
            const int b = wave * 32 + (MT) * 16 + quad * 4 + r; \
            hw[(long)b * H_ + j0 + jj] = (__bf16)hn; \
            if (cell) out[((long)b * T_ + t) * H_ + j0 + jj] = hn; \
        } \
    }

// Persistent kernel: 256 blocks (1/CU). Blocks [0,128) = cell0, [128,256) = cell1.
// Block owns 8 h-columns x 4 gates (32 gate-rows) of its cell; weights live in LDS
// for the whole sequence. Phase p: cell0 computes t=p, cell1 computes t=p-1
// (classic 2-cell pipeline); one grid barrier between phases.
__global__ __launch_bounds__(256, 1) void lstm_persist(
    const float* __restrict__ x,
    const float* __restrict__ Wih0, const float* __restrict__ Whh0,
    const float* __restrict__ Wih1, const float* __restrict__ Whh1,
    const float* __restrict__ bih0, const float* __restrict__ bhh0,
    const float* __restrict__ bih1, const float* __restrict__ bhh1,
    __bf16* __restrict__ h0a, __bf16* __restrict__ h0b,
    __bf16* __restrict__ h1a, __bf16* __restrict__ h1b,
    unsigned* bar, const __bf16* __restrict__ xb, float* __restrict__ out)
{
    const int cell = blockIdx.x >> 7;
    const int cidx = blockIdx.x & 127;
    const int j0   = cidx << 3;            // 8 h-columns per block

    __shared__ __align__(16) __bf16 wB[32][WROW];   // 131,584 B resident weights
    __shared__ float bb[32];                        // bias sums (n-indexed)

    const int tid  = threadIdx.x;
    const int wave = tid >> 6;
    const int lane = tid & 63;
    const int quad = lane >> 4;
    const int lrow = lane & 15;
    const int jj   = lane & 7;
    const bool hi  = (lane & 8) != 0;

    const float* Wih = cell ? Wih1 : Wih0;
    const float* Whh = cell ? Whh1 : Whh0;

    // ---- one-time: stage this block's 32 gate-rows x K=2048 weights into LDS ----
    // row n = gate*8 + jj maps to weight row gate*1024 + j0 + jj; k<1024 from Wih, else Whh.
    for (int e = tid; e < 32 * 512; e += 256) {       // float4 granules, coalesced
        int n  = e >> 9;
        int k  = (e & 511) << 2;
        int wr = ((n >> 3) << 10) + j0 + (n & 7);
        const float* src = (k < 1024) ? (Wih + (long)wr * 1024 + k)
                                      : (Whh + (long)wr * 1024 + (k - 1024));
        float4 v = *(const float4*)src;
        bf16x4 o = { (__bf16)v.x, (__bf16)v.y, (__bf16)v.z, (__bf16)v.w };
        *(bf16x4*)&wB[n][k] = o;
    }
    if (tid < 32) {
        int wr = ((tid >> 3) << 10) + j0 + (tid & 7);
        bb[tid] = cell ? (bih1[wr] + bhh1[wr]) : (bih0[wr] + bhh0[wr]);
    }
    __syncthreads();

    const int arow0 = wave * 32 + lrow;   // A-fragment row, M-tile 0
    const int arow1 = arow0 + 16;         // M-tile 1

    // c-state in registers: this block exclusively owns its (b, j) slice forever.
    float creg[2][4] = {};

    for (int p = 0; p <= T_; ++p) {
        const int  t      = cell ? (p - 1) : p;
        const bool active = cell ? (p >= 1) : (p < T_);
        if (active) {
            // h parity: h0(t) in (t&1 ? h0b : h0a); h1(t) in (t&1 ? h1b : h1a)
            const __bf16* srcPh0 = (t & 1) ? h0b : h0a;              // cell1: h0(t)
            const __bf16* srcPh1 = cell ? ((t & 1) ? h1a : h1b)      // h1(t-1)
                                        : ((t & 1) ? h0a : h0b);     // h0(t-1)
            __bf16* hw = cell ? ((t & 1) ? h1b : h1a)
                              : ((t & 1) ? h0b : h0a);

            f32x4 acc00 = {}, acc01 = {}, acc10 = {}, acc11 = {};

            // ---- phase 0: k in [0,1024) ----
            if (cell == 0) {
                if (xb) {   // pre-converted bf16 x
                    const __bf16* pa = xb + ((long)arow0 * T_ + t) * F_ + quad * 8;
                    const __bf16* pb = xb + ((long)arow1 * T_ + t) * F_ + quad * 8;
                    #pragma unroll 8
                    for (int ks = 0; ks < 32; ++ks) {
                        bf16x8 a0_ = *(const bf16x8*)(pa + ks * 32);
                        bf16x8 a1_ = *(const bf16x8*)(pb + ks * 32);
                        MFMA4(a0_, a1_, ks * 32);
                    }
                } else {    // fp32 x, convert inline
                    const float* pa = x + ((long)arow0 * T_ + t) * F_ + quad * 8;
                    const float* pb = x + ((long)arow1 * T_ + t) * F_ + quad * 8;
                    #pragma unroll 4
                    for (int ks = 0; ks < 32; ++ks) {
                        float4 va = *(const float4*)(pa + ks * 32);
                        float4 vb = *(const float4*)(pa + ks * 32 + 4);
                        float4 vc = *(const float4*)(pb + ks * 32);
                        float4 vd = *(const float4*)(pb + ks * 32 + 4);
                        bf16x8 a0_ = { (__bf16)va.x, (__bf16)va.y, (__bf16)va.z, (__bf16)va.w,
                                       (__bf16)vb.x, (__bf16)vb.y, (__bf16)vb.z, (__bf16)vb.w };
                        bf16x8 a1_ = { (__bf16)vc.x, (__bf16)vc.y, (__bf16)vc.z, (__bf16)vc.w,
                                       (__bf16)vd.x, (__bf16)vd.y, (__bf16)vd.z, (__bf16)vd.w };
                        MFMA4(a0_, a1_, ks * 32);
                    }
                }
            } else {
                const __bf16* pa = srcPh0 + (long)arow0 * H_ + quad * 8;
                const __bf16* pb = srcPh0 + (long)arow1 * H_ + quad * 8;
                #pragma unroll 8
                for (int ks = 0; ks < 32; ++ks) {
                    bf16x8 a0_ = *(const bf16x8*)(pa + ks * 32);
                    bf16x8 a1_ = *(const bf16x8*)(pb + ks * 32);
                    MFMA4(a0_, a1_, ks * 32);
                }
            }
            // ---- phase 1: k in [1024,2048) (recurrent h) ----
            {
                const __bf16* pa = srcPh1 + (long)arow0 * H_ + quad * 8;
                const __bf16* pb = srcPh1 + (long)arow1 * H_ + quad * 8;
                #pragma unroll 8
                for (int ks = 0; ks < 32; ++ks) {
                    bf16x8 a0_ = *(const bf16x8*)(pa + ks * 32);
                    bf16x8 a1_ = *(const bf16x8*)(pb + ks * 32);
                    MFMA4(a0_, a1_, 1024 + ks * 32);
                }
            }

            const float bi  = bb[jj];
            const float bf_ = bb[8 + jj];
            const float bg  = bb[16 + jj];
            const float bo  = bb[24 + jj];
            EPI(0, acc00, acc01);
            EPI(1, acc10, acc11);
        }
        if (p < T_) grid_barrier(bar, bar + 32);
    }
}

extern "C" void kernel_launch(void* const* d_in, const int* in_sizes, int n_in,
                              void* d_out, int out_size, void* d_ws, size_t ws_size,
                              hipStream_t stream)
{
    const float* x    = (const float*)d_in[0];
    const float* Wih0 = (const float*)d_in[1];
    const float* bih0 = (const float*)d_in[2];
    const float* Whh0 = (const float*)d_in[3];
    const float* bhh0 = (const float*)d_in[4];
    const float* Wih1 = (const float*)d_in[5];
    const float* bih1 = (const float*)d_in[6];
    const float* Whh1 = (const float*)d_in[7];
    const float* bhh1 = (const float*)d_in[8];
    float* out = (float*)d_out;

    // ws layout: [bar 4K] [h0a 256K][h0b 256K][h1a 256K][h1b 256K] [xb 64M optional]
    char* ws = (char*)d_ws;
    unsigned* bar = (unsigned*)ws;
    __bf16* h0a = (__bf16*)(ws + 4096);
    __bf16* h0b = (__bf16*)(ws + 4096 + (256 << 10));
    __bf16* h1a = (__bf16*)(ws + 4096 + (512 << 10));
    __bf16* h1b = (__bf16*)(ws + 4096 + (768 << 10));
    const __bf16* xb = nullptr;

    const size_t XB_OFF = 4096 + (1 << 20);
    if (ws_size >= XB_OFF + ((size_t)64 << 20)) {
        __bf16* xbw = (__bf16*)(ws + XB_OFF);
        k_cvt<<<dim3(16384), dim3(256), 0, stream>>>(x, xbw, B_ * T_ * F_);
        xb = xbw;
    }
    k_init<<<dim3(512), dim3(256), 0, stream>>>(h0b, h1b, bar);

    void* args[] = {
        (void*)&x, (void*)&Wih0, (void*)&Whh0, (void*)&Wih1, (void*)&Whh1,
        (void*)&bih0, (void*)&bhh0, (void*)&bih1, (void*)&bhh1,
        (void*)&h0a, (void*)&h0b, (void*)&h1a, (void*)&h1b,
        (void*)&bar, (void*)&xb, (void*)&out
    };
    hipError_t err = hipLaunchCooperativeKernel((const void*)lstm_persist,
                                                dim3(256), dim3(256), args, 0, stream);
    if (err != hipSuccess) {
        // Fallback: 256 blocks at 1 block/CU on 256 CUs are co-resident in practice;
        // the hand-rolled barrier does not depend on cooperative-launch metadata.
        lstm_persist<<<dim3(256), dim3(256), 0, stream>>>(
            x, Wih0, Whh0, Wih1, Whh1, bih0, bhh0, bih1, bhh1,
            h0a, h0b, h1a, h1b, bar, xb, out);
    }
    (void)in_sizes; (void)n_in; (void)out_size;
}

// Round 2
// 7381.405 us; speedup vs baseline: 1.6716x; 1.5639x over previous
//
#include <hip/hip_runtime.h>

// Problem constants
#define B_ 128
#define T_ 256
#define F_ 1024
#define H_ 1024

typedef __bf16 bf16x8 __attribute__((ext_vector_type(8)));
typedef __bf16 bf16x4 __attribute__((ext_vector_type(4)));
typedef float f32x4 __attribute__((ext_vector_type(4)));

// LDS weight tile row stride (bf16 elems): 2056*2 = 4112 B (16B-aligned rows).
#define WROW 2056

__device__ __forceinline__ float sigf(float v)  { return 1.0f / (1.0f + __expf(-v)); }
// NaN-free tanh
__device__ __forceinline__ float tanhfast(float x) { return 1.0f - 2.0f / (1.0f + __expf(2.0f * x)); }

// fp32 -> bf16 (n must equal 8*256*gridDim)
__global__ void k_cvt(const float* __restrict__ src, __bf16* __restrict__ dst, int n) {
    int i = (blockIdx.x * 256 + threadIdx.x) * 8;
    if (i + 7 < n) {
        float4 a = *(const float4*)(src + i);
        float4 b = *(const float4*)(src + i + 4);
        bf16x8 o = { (__bf16)a.x, (__bf16)a.y, (__bf16)a.z, (__bf16)a.w,
                     (__bf16)b.x, (__bf16)b.y, (__bf16)b.z, (__bf16)b.w };
        *(bf16x8*)(dst + i) = o;
    }
}

// Zero the t=-1 h buffers and the grid-barrier state (ws is poisoned).
__global__ void k_init(__bf16* h0b, __bf16* h1b, unsigned* bar) {
    int i = blockIdx.x * 256 + threadIdx.x;   // 512 x 256 = 131072 exactly
    h0b[i] = (__bf16)0.0f;
    h1b[i] = (__bf16)0.0f;
    if (i < 64) bar[i] = 0u;
}

// One K=32 slice for 2 M-tiles x 2 N-tiles; B from resident LDS weights.
#define STEP(A0, A1, KW) do { \
    bf16x8 b0_ = *(const bf16x8*)&wB[lrow][(KW) + quad * 8]; \
    bf16x8 b1_ = *(const bf16x8*)&wB[16 + lrow][(KW) + quad * 8]; \
    acc00 = __builtin_amdgcn_mfma_f32_16x16x32_bf16(A0, b0_, acc00, 0, 0, 0); \
    acc01 = __builtin_amdgcn_mfma_f32_16x16x32_bf16(A0, b1_, acc01, 0, 0, 0); \
    acc10 = __builtin_amdgcn_mfma_f32_16x16x32_bf16(A1, b0_, acc10, 0, 0, 0); \
    acc11 = __builtin_amdgcn_mfma_f32_16x16x32_bf16(A1, b1_, acc11, 0, 0, 0); \
} while (0)

// K-half loop (512 of K), bf16 A source. WBASE: 0 = Wih cols, 1024 = Whh cols.
#define KLOOP_BF16(SRC, STRIDE, WBASE) do { \
    const __bf16* pa_ = (SRC) + (long)arow0 * (STRIDE) + kbase + quad * 8; \
    const __bf16* pb_ = (SRC) + (long)arow1 * (STRIDE) + kbase + quad * 8; \
    _Pragma("unroll 8") \
    for (int ks_ = 0; ks_ < 16; ++ks_) { \
        bf16x8 a0_ = *(const bf16x8*)(pa_ + ks_ * 32); \
        bf16x8 a1_ = *(const bf16x8*)(pb_ + ks_ * 32); \
        STEP(a0_, a1_, (WBASE) + kbase + ks_ * 32); \
    } \
} while (0)

// Same, fp32 A source with inline conversion (x fallback path).
#define KLOOP_F32(SRC, STRIDE, WBASE) do { \
    const float* pa_ = (SRC) + (long)arow0 * (STRIDE) + kbase + quad * 8; \
    const float* pb_ = (SRC) + (long)arow1 * (STRIDE) + kbase + quad * 8; \
    _Pragma("unroll 4") \
    for (int ks_ = 0; ks_ < 16; ++ks_) { \
        float4 va_ = *(const float4*)(pa_ + ks_ * 32); \
        float4 vb_ = *(const float4*)(pa_ + ks_ * 32 + 4); \
        float4 vc_ = *(const float4*)(pb_ + ks_ * 32); \
        float4 vd_ = *(const float4*)(pb_ + ks_ * 32 + 4); \
        bf16x8 a0_ = { (__bf16)va_.x, (__bf16)va_.y, (__bf16)va_.z, (__bf16)va_.w, \
                       (__bf16)vb_.x, (__bf16)vb_.y, (__bf16)vb_.z, (__bf16)vb_.w }; \
        bf16x8 a1_ = { (__bf16)vc_.x, (__bf16)vc_.y, (__bf16)vc_.z, (__bf16)vc_.w, \
                       (__bf16)vd_.x, (__bf16)vd_.y, (__bf16)vd_.z, (__bf16)vd_.w }; \
        STEP(a0_, a1_, (WBASE) + kbase + ks_ * 32); \
    } \
} while (0)

#define ZACC() do { \
    acc00 = (f32x4){0.f,0.f,0.f,0.f}; acc01 = (f32x4){0.f,0.f,0.f,0.f}; \
    acc10 = (f32x4){0.f,0.f,0.f,0.f}; acc11 = (f32x4){0.f,0.f,0.f,0.f}; \
} while (0)

// Epilogue for one M-tile (waves 0-3 only). Lanes jj / jj+8 hold (i,g)/(f,o);
// one shfl_xor(8) pair reunites the 4 gates; both lanes compute identical c/h,
// only the low lane stores.
#define EPI(MT, ACC_A, ACC_B, HW, TT, WOUT) \
    _Pragma("unroll") \
    for (int r = 0; r < 4; ++r) { \
        float v0 = (ACC_A)[r], v1 = (ACC_B)[r]; \
        float q0 = __shfl_xor(v0, 8); \
        float q1 = __shfl_xor(v1, 8); \
        float iv = (hi ? q0 : v0) + bi; \
        float fv = (hi ? v0 : q0) + bf_; \
        float gv = (hi ? q1 : v1) + bg; \
        float ov = (hi ? v1 : q1) + bo; \
        float cn = sigf(fv) * creg[MT][r] + sigf(iv) * tanhfast(gv); \
        creg[MT][r] = cn; \
        float hn = sigf(ov) * tanhfast(cn); \
        if (!hi) { \
            const int b = (wave << 5) + (MT) * 16 + (quad << 2) + r; \
            (HW)[(long)b * H_ + j0 + jj] = (__bf16)hn; \
            if (WOUT) out[((long)b * T_ + (TT)) * H_ + j0 + jj] = hn; \
        } \
    }

// Cross-wave K-half reduce (wave w+4 -> wave w) then epilogue on waves 0-3.
#define REDUCE_EPI(HW, TT, WOUT) do { \
    if (wave >= 4) { \
        red[wave - 4][lane][0] = acc00; red[wave - 4][lane][1] = acc01; \
        red[wave - 4][lane][2] = acc10; red[wave - 4][lane][3] = acc11; \
    } \
    __syncthreads(); \
    if (wave < 4) { \
        acc00 += red[wave][lane][0]; acc01 += red[wave][lane][1]; \
        acc10 += red[wave][lane][2]; acc11 += red[wave][lane][3]; \
        const float bi  = bb[jj]; \
        const float bf_ = bb[8 + jj]; \
        const float bg  = bb[16 + jj]; \
        const float bo  = bb[24 + jj]; \
        EPI(0, acc00, acc01, HW, TT, WOUT); \
        EPI(1, acc10, acc11, HW, TT, WOUT); \
    } \
} while (0)

// Persistent kernel: 256 blocks (1/CU), 512 threads (8 waves). Blocks [0,128)=cell0,
// [128,256)=cell1. Block owns 8 h-columns x 4 gates; weights resident in LDS.
// Wave w and w+4 compute the same 2 M-tiles over opposite K-halves (split-K),
// reduced via LDS. cell0 overlaps the grid barrier with the barrier-independent
// x-projection of the NEXT timestep (arrive -> x-matmul -> poll).
__global__ __launch_bounds__(512, 2) void lstm_persist(
    const float* __restrict__ x,
    const float* __restrict__ Wih0, const float* __restrict__ Whh0,
    const float* __restrict__ Wih1, const float* __restrict__ Whh1,
    const float* __restrict__ bih0, const float* __restrict__ bhh0,
    const float* __restrict__ bih1, const float* __restrict__ bhh1,
    __bf16* __restrict__ h0a, __bf16* __restrict__ h0b,
    __bf16* __restrict__ h1a, __bf16* __restrict__ h1b,
    unsigned* bar, const __bf16* __restrict__ xb, float* __restrict__ out)
{
    const int cell = blockIdx.x >> 7;
    const int cidx = blockIdx.x & 127;
    const int j0   = cidx << 3;            // 8 h-columns per block

    __shared__ __align__(16) __bf16 wB[32][WROW];   // 131,584 B resident weights
    __shared__ __align__(16) f32x4  red[4][64][4];  // 16,384 B split-K partials
    __shared__ float bb[32];                        // bias sums

    const int tid  = threadIdx.x;
    const int wave = tid >> 6;             // 0..7
    const int lane = tid & 63;
    const int quad = lane >> 4;
    const int lrow = lane & 15;
    const int jj   = lane & 7;
    const bool hi  = (lane & 8) != 0;

    const int kbase = (wave >> 2) << 9;              // 0 or 512: K-half per wave
    const int arow0 = ((wave & 3) << 5) + lrow;      // M-tile pair shared by w, w+4
    const int arow1 = arow0 + 16;

    unsigned* cnt = bar;
    unsigned* gen = bar + 32;

    const float* Wih = cell ? Wih1 : Wih0;
    const float* Whh = cell ? Whh1 : Whh0;

    // ---- one-time: stage 32 gate-rows x K=2048 weights into LDS ----
    for (int e = tid; e < 32 * 512; e += 512) {
        int n  = e >> 9;
        int k  = (e & 511) << 2;
        int wr = ((n >> 3) << 10) + j0 + (n & 7);
        const float* src = (k < 1024) ? (Wih + (long)wr * 1024 + k)
                                      : (Whh + (long)wr * 1024 + (k - 1024));
        float4 v = *(const float4*)src;
        bf16x4 o = { (__bf16)v.x, (__bf16)v.y, (__bf16)v.z, (__bf16)v.w };
        *(bf16x4*)&wB[n][k] = o;
    }
    if (tid < 32) {
        int wr = ((tid >> 3) << 10) + j0 + (tid & 7);
        bb[tid] = cell ? (bih1[wr] + bhh1[wr]) : (bih0[wr] + bhh0[wr]);
    }
    __syncthreads();

    float creg[2][4] = {};   // c-state (waves 0-3; block owns its (b,j) slice)
    f32x4 acc00, acc01, acc10, acc11;
    ZACC();

    // prologue: cell0 x-part for t=0 (barrier-independent)
    if (cell == 0) {
        if (xb) KLOOP_BF16(xb + 0, (long)T_ * F_, 0);
        else    KLOOP_F32 (x  + 0, (long)T_ * F_, 0);
    }

    for (int p = 0; p <= T_; ++p) {
        if (cell == 0) {
            if (p < T_) {
                const int t = p;
                const __bf16* hprev = (t & 1) ? h0a : h0b;   // h0(t-1)
                __bf16* hw          = (t & 1) ? h0b : h0a;   // h0(t)
                KLOOP_BF16(hprev, H_, 1024);                 // acc already holds x-part(t)
                REDUCE_EPI(hw, t, false);
            }
        } else {
            if (p >= 1) {
                const int t = p - 1;
                ZACC();
                const __bf16* s0 = (t & 1) ? h0b : h0a;      // h0(t)
                const __bf16* s1 = (t & 1) ? h1a : h1b;      // h1(t-1)
                __bf16* hw       = (t & 1) ? h1b : h1a;      // h1(t)
                KLOOP_BF16(s0, H_, 0);
                KLOOP_BF16(s1, H_, 1024);
                REDUCE_EPI(hw, t, true);
            }
        }

        if (p < T_) {
            __syncthreads();           // all epilogue writes issued & drained
            unsigned g = 0;
            if (tid == 0) {
                __threadfence();       // release: wbl2 -> h/out visible at LLC
                g = __hip_atomic_load(gen, __ATOMIC_RELAXED, __HIP_MEMORY_SCOPE_AGENT);
                unsigned a = __hip_atomic_fetch_add(cnt, 1u, __ATOMIC_RELAXED,
                                                    __HIP_MEMORY_SCOPE_AGENT);
                if (a == 255u) {
                    __hip_atomic_store(cnt, 0u, __ATOMIC_RELAXED, __HIP_MEMORY_SCOPE_AGENT);
                    __hip_atomic_store(gen, g + 1u, __ATOMIC_RELEASE, __HIP_MEMORY_SCOPE_AGENT);
                }
            }
            // ---- barrier-hidden work: next timestep's x-projection (cell0) ----
            if (cell == 0) {
                ZACC();
                if (p + 1 < T_) {
                    if (xb) KLOOP_BF16(xb + (long)(p + 1) * F_, (long)T_ * F_, 0);
                    else    KLOOP_F32 (x  + (long)(p + 1) * F_, (long)T_ * F_, 0);
                }
            }
            if (tid == 0) {
                // relaxed poll (no per-poll buffer_inv); acquire-load fallback for safety
                for (;;) {
                    bool done = false;
                    for (int it = 0; it < 256; ++it) {
                        if (__hip_atomic_load(gen, __ATOMIC_RELAXED,
                                              __HIP_MEMORY_SCOPE_AGENT) != g) { done = true; break; }
                        __builtin_amdgcn_s_sleep(2);
                    }
                    if (done) break;
                    if (__hip_atomic_load(gen, __ATOMIC_ACQUIRE,
                                          __HIP_MEMORY_SCOPE_AGENT) != g) break;
                }
                __builtin_amdgcn_fence(__ATOMIC_ACQUIRE, "agent");  // single inv
            }
            __syncthreads();
        }
    }
}

extern "C" void kernel_launch(void* const* d_in, const int* in_sizes, int n_in,
                              void* d_out, int out_size, void* d_ws, size_t ws_size,
                              hipStream_t stream)
{
    const float* x    = (const float*)d_in[0];
    const float* Wih0 = (const float*)d_in[1];
    const float* bih0 = (const float*)d_in[2];
    const float* Whh0 = (const float*)d_in[3];
    const float* bhh0 = (const float*)d_in[4];
    const float* Wih1 = (const float*)d_in[5];
    const float* bih1 = (const float*)d_in[6];
    const float* Whh1 = (const float*)d_in[7];
    const float* bhh1 = (const float*)d_in[8];
    float* out = (float*)d_out;

    // ws layout: [bar 4K] [h0a 256K][h0b 256K][h1a 256K][h1b 256K] [xb 64M optional]
    char* ws = (char*)d_ws;
    unsigned* bar = (unsigned*)ws;
    __bf16* h0a = (__bf16*)(ws + 4096);
    __bf16* h0b = (__bf16*)(ws + 4096 + (256 << 10));
    __bf16* h1a = (__bf16*)(ws + 4096 + (512 << 10));
    __bf16* h1b = (__bf16*)(ws + 4096 + (768 << 10));
    const __bf16* xb = nullptr;

    const size_t XB_OFF = 4096 + (1 << 20);
    if (ws_size >= XB_OFF + ((size_t)64 << 20)) {
        __bf16* xbw = (__bf16*)(ws + XB_OFF);
        k_cvt<<<dim3(16384), dim3(256), 0, stream>>>(x, xbw, B_ * T_ * F_);
        xb = xbw;
    }
    k_init<<<dim3(512), dim3(256), 0, stream>>>(h0b, h1b, bar);

    void* args[] = {
        (void*)&x, (void*)&Wih0, (void*)&Whh0, (void*)&Wih1, (void*)&Whh1,
        (void*)&bih0, (void*)&bhh0, (void*)&bih1, (void*)&bhh1,
        (void*)&h0a, (void*)&h0b, (void*)&h1a, (void*)&h1b,
        (void*)&bar, (void*)&xb, (void*)&out
    };
    hipError_t err = hipLaunchCooperativeKernel((const void*)lstm_persist,
                                                dim3(256), dim3(512), args, 0, stream);
    if (err != hipSuccess) {
        // Fallback: 256 blocks at 1 block/CU are co-resident; the hand-rolled
        // barrier does not depend on cooperative-launch metadata.
        lstm_persist<<<dim3(256), dim3(512), 0, stream>>>(
            x, Wih0, Whh0, Wih1, Whh1, bih0, bhh0, bih1, bhh1,
            h0a, h0b, h1a, h1b, bar, xb, out);
    }
    (void)in_sizes; (void)n_in; (void)out_size;
}

// Round 3
// 7375.971 us; speedup vs baseline: 1.6728x; 1.0007x over previous
//
#include <hip/hip_runtime.h>

// Problem constants
#define B_ 128
#define T_ 256
#define F_ 1024
#define H_ 1024

typedef __bf16 bf16x8 __attribute__((ext_vector_type(8)));
typedef __bf16 bf16x4 __attribute__((ext_vector_type(4)));
typedef float f32x4 __attribute__((ext_vector_type(4)));

// LDS weight tile row stride (bf16 elems): 2056*2 = 4112 B (16B-aligned rows).
#define WROW 2056

__device__ __forceinline__ float sigf(float v)  { return 1.0f / (1.0f + __expf(-v)); }
// NaN-free tanh
__device__ __forceinline__ float tanhfast(float x) { return 1.0f - 2.0f / (1.0f + __expf(2.0f * x)); }

// fp32 -> bf16 (n must equal 8*256*gridDim)
__global__ void k_cvt(const float* __restrict__ src, __bf16* __restrict__ dst, int n) {
    int i = (blockIdx.x * 256 + threadIdx.x) * 8;
    if (i + 7 < n) {
        float4 a = *(const float4*)(src + i);
        float4 b = *(const float4*)(src + i + 4);
        bf16x8 o = { (__bf16)a.x, (__bf16)a.y, (__bf16)a.z, (__bf16)a.w,
                     (__bf16)b.x, (__bf16)b.y, (__bf16)b.z, (__bf16)b.w };
        *(bf16x8*)(dst + i) = o;
    }
}

// Zero the t=-1 h buffers and the grid-barrier state (ws is poisoned).
__global__ void k_init(__bf16* h0b, __bf16* h1b, unsigned* bar) {
    int i = blockIdx.x * 256 + threadIdx.x;   // 512 x 256 = 131072 exactly
    h0b[i] = (__bf16)0.0f;
    h1b[i] = (__bf16)0.0f;
    if (i < 64) bar[i] = 0u;
}

// One K=32 slice for 2 M-tiles x 2 N-tiles; B from resident LDS weights.
#define STEP(A0, A1, KW) do { \
    bf16x8 b0_ = *(const bf16x8*)&wB[lrow][(KW) + quad * 8]; \
    bf16x8 b1_ = *(const bf16x8*)&wB[16 + lrow][(KW) + quad * 8]; \
    acc00 = __builtin_amdgcn_mfma_f32_16x16x32_bf16(A0, b0_, acc00, 0, 0, 0); \
    acc01 = __builtin_amdgcn_mfma_f32_16x16x32_bf16(A0, b1_, acc01, 0, 0, 0); \
    acc10 = __builtin_amdgcn_mfma_f32_16x16x32_bf16(A1, b0_, acc10, 0, 0, 0); \
    acc11 = __builtin_amdgcn_mfma_f32_16x16x32_bf16(A1, b1_, acc11, 0, 0, 0); \
} while (0)

// K-half loop (512 of K), bf16 A source, register-ring prefetch depth 8
// (16 loads / 16 KB per wave in flight). Fully unrolled -> static ring indices.
// WBASE: 0 = Wih cols, 1024 = Whh cols.
#define KLOOP_BF16(SRC, STRIDE, WBASE) do { \
    const __bf16* pa_ = (SRC) + (long)arow0 * (STRIDE) + kbase + quad * 8; \
    const __bf16* pb_ = (SRC) + (long)arow1 * (STRIDE) + kbase + quad * 8; \
    bf16x8 ra_[8], rb_[8]; \
    _Pragma("unroll") \
    for (int i_ = 0; i_ < 8; ++i_) { \
        ra_[i_] = *(const bf16x8*)(pa_ + i_ * 32); \
        rb_[i_] = *(const bf16x8*)(pb_ + i_ * 32); \
    } \
    _Pragma("unroll") \
    for (int ks_ = 0; ks_ < 16; ++ks_) { \
        bf16x8 a0_ = ra_[ks_ & 7]; \
        bf16x8 a1_ = rb_[ks_ & 7]; \
        if (ks_ < 8) { \
            ra_[ks_ & 7] = *(const bf16x8*)(pa_ + (ks_ + 8) * 32); \
            rb_[ks_ & 7] = *(const bf16x8*)(pb_ + (ks_ + 8) * 32); \
        } \
        STEP(a0_, a1_, (WBASE) + kbase + ks_ * 32); \
    } \
} while (0)

// Same, fp32 A source with inline conversion (x fallback path), prefetch depth 4.
#define KLOOP_F32(SRC, STRIDE, WBASE) do { \
    const float* pa_ = (SRC) + (long)arow0 * (STRIDE) + kbase + quad * 8; \
    const float* pb_ = (SRC) + (long)arow1 * (STRIDE) + kbase + quad * 8; \
    float4 rA_[4], rB_[4], rC_[4], rD_[4]; \
    _Pragma("unroll") \
    for (int i_ = 0; i_ < 4; ++i_) { \
        rA_[i_] = *(const float4*)(pa_ + i_ * 32); \
        rB_[i_] = *(const float4*)(pa_ + i_ * 32 + 4); \
        rC_[i_] = *(const float4*)(pb_ + i_ * 32); \
        rD_[i_] = *(const float4*)(pb_ + i_ * 32 + 4); \
    } \
    _Pragma("unroll") \
    for (int ks_ = 0; ks_ < 16; ++ks_) { \
        float4 va_ = rA_[ks_ & 3], vb_ = rB_[ks_ & 3]; \
        float4 vc_ = rC_[ks_ & 3], vd_ = rD_[ks_ & 3]; \
        if (ks_ < 12) { \
            rA_[ks_ & 3] = *(const float4*)(pa_ + (ks_ + 4) * 32); \
            rB_[ks_ & 3] = *(const float4*)(pa_ + (ks_ + 4) * 32 + 4); \
            rC_[ks_ & 3] = *(const float4*)(pb_ + (ks_ + 4) * 32); \
            rD_[ks_ & 3] = *(const float4*)(pb_ + (ks_ + 4) * 32 + 4); \
        } \
        bf16x8 a0_ = { (__bf16)va_.x, (__bf16)va_.y, (__bf16)va_.z, (__bf16)va_.w, \
                       (__bf16)vb_.x, (__bf16)vb_.y, (__bf16)vb_.z, (__bf16)vb_.w }; \
        bf16x8 a1_ = { (__bf16)vc_.x, (__bf16)vc_.y, (__bf16)vc_.z, (__bf16)vc_.w, \
                       (__bf16)vd_.x, (__bf16)vd_.y, (__bf16)vd_.z, (__bf16)vd_.w }; \
        STEP(a0_, a1_, (WBASE) + kbase + ks_ * 32); \
    } \
} while (0)

#define ZACC() do { \
    acc00 = (f32x4){0.f,0.f,0.f,0.f}; acc01 = (f32x4){0.f,0.f,0.f,0.f}; \
    acc10 = (f32x4){0.f,0.f,0.f,0.f}; acc11 = (f32x4){0.f,0.f,0.f,0.f}; \
} while (0)

// Epilogue for one M-tile (waves 0-3 only). Lanes jj / jj+8 hold (i,g)/(f,o);
// one shfl_xor(8) pair reunites the 4 gates; both lanes compute identical c/h,
// only the low lane stores.
#define EPI(MT, ACC_A, ACC_B, HW, TT, WOUT) \
    _Pragma("unroll") \
    for (int r = 0; r < 4; ++r) { \
        float v0 = (ACC_A)[r], v1 = (ACC_B)[r]; \
        float q0 = __shfl_xor(v0, 8); \
        float q1 = __shfl_xor(v1, 8); \
        float iv = (hi ? q0 : v0) + bi; \
        float fv = (hi ? v0 : q0) + bf_; \
        float gv = (hi ? q1 : v1) + bg; \
        float ov = (hi ? v1 : q1) + bo; \
        float cn = sigf(fv) * creg[MT][r] + sigf(iv) * tanhfast(gv); \
        creg[MT][r] = cn; \
        float hn = sigf(ov) * tanhfast(cn); \
        if (!hi) { \
            const int b = (wave << 5) + (MT) * 16 + (quad << 2) + r; \
            (HW)[(long)b * H_ + j0 + jj] = (__bf16)hn; \
            if (WOUT) out[((long)b * T_ + (TT)) * H_ + j0 + jj] = hn; \
        } \
    }

// Cross-wave K-half reduce (wave w+4 -> wave w) then epilogue on waves 0-3.
// red layout is lane-major (red[w][i][lane]) -> all b32 accesses conflict-free.
#define REDUCE_EPI(HW, TT, WOUT) do { \
    if (wave >= 4) { \
        _Pragma("unroll") \
        for (int i_ = 0; i_ < 4; ++i_) { \
            red[wave - 4][i_     ][lane] = acc00[i_]; \
            red[wave - 4][i_ + 4 ][lane] = acc01[i_]; \
            red[wave - 4][i_ + 8 ][lane] = acc10[i_]; \
            red[wave - 4][i_ + 12][lane] = acc11[i_]; \
        } \
    } \
    __syncthreads(); \
    if (wave < 4) { \
        _Pragma("unroll") \
        for (int i_ = 0; i_ < 4; ++i_) { \
            acc00[i_] += red[wave][i_     ][lane]; \
            acc01[i_] += red[wave][i_ + 4 ][lane]; \
            acc10[i_] += red[wave][i_ + 8 ][lane]; \
            acc11[i_] += red[wave][i_ + 12][lane]; \
        } \
        const float bi  = bb[jj]; \
        const float bf_ = bb[8 + jj]; \
        const float bg  = bb[16 + jj]; \
        const float bo  = bb[24 + jj]; \
        EPI(0, acc00, acc01, HW, TT, WOUT); \
        EPI(1, acc10, acc11, HW, TT, WOUT); \
    } \
} while (0)

// Persistent kernel: 256 blocks (1/CU), 512 threads (8 waves). Blocks [0,128)=cell0,
// [128,256)=cell1. Block owns 8 h-columns x 4 gates; weights resident in LDS.
// Wave w and w+4 compute the same 2 M-tiles over opposite K-halves (split-K),
// reduced via LDS. cell0 overlaps the grid barrier with the barrier-independent
// x-projection of the NEXT timestep (arrive -> x-matmul -> poll).
// LDS = 148 KB -> 1 block/CU regardless; declare min-waves 1 so the register
// allocator can use the full 256-VGPR budget for the prefetch rings.
__global__ __launch_bounds__(512, 1) void lstm_persist(
    const float* __restrict__ x,
    const float* __restrict__ Wih0, const float* __restrict__ Whh0,
    const float* __restrict__ Wih1, const float* __restrict__ Whh1,
    const float* __restrict__ bih0, const float* __restrict__ bhh0,
    const float* __restrict__ bih1, const float* __restrict__ bhh1,
    __bf16* __restrict__ h0a, __bf16* __restrict__ h0b,
    __bf16* __restrict__ h1a, __bf16* __restrict__ h1b,
    unsigned* bar, const __bf16* __restrict__ xb, float* __restrict__ out)
{
    const int cell = blockIdx.x >> 7;
    const int cidx = blockIdx.x & 127;
    const int j0   = cidx << 3;            // 8 h-columns per block

    __shared__ __align__(16) __bf16 wB[32][WROW];   // 131,584 B resident weights
    __shared__ __align__(16) float  red[4][16][64]; // 16,384 B split-K partials (lane-major)
    __shared__ float bb[32];                        // bias sums

    const int tid  = threadIdx.x;
    const int wave = tid >> 6;             // 0..7
    const int lane = tid & 63;
    const int quad = lane >> 4;
    const int lrow = lane & 15;
    const int jj   = lane & 7;
    const bool hi  = (lane & 8) != 0;

    const int kbase = (wave >> 2) << 9;              // 0 or 512: K-half per wave
    const int arow0 = ((wave & 3) << 5) + lrow;      // M-tile pair shared by w, w+4
    const int arow1 = arow0 + 16;

    unsigned* cnt = bar;
    unsigned* gen = bar + 32;

    const float* Wih = cell ? Wih1 : Wih0;
    const float* Whh = cell ? Whh1 : Whh0;

    // ---- one-time: stage 32 gate-rows x K=2048 weights into LDS ----
    for (int e = tid; e < 32 * 512; e += 512) {
        int n  = e >> 9;
        int k  = (e & 511) << 2;
        int wr = ((n >> 3) << 10) + j0 + (n & 7);
        const float* src = (k < 1024) ? (Wih + (long)wr * 1024 + k)
                                      : (Whh + (long)wr * 1024 + (k - 1024));
        float4 v = *(const float4*)src;
        bf16x4 o = { (__bf16)v.x, (__bf16)v.y, (__bf16)v.z, (__bf16)v.w };
        *(bf16x4*)&wB[n][k] = o;
    }
    if (tid < 32) {
        int wr = ((tid >> 3) << 10) + j0 + (tid & 7);
        bb[tid] = cell ? (bih1[wr] + bhh1[wr]) : (bih0[wr] + bhh0[wr]);
    }
    __syncthreads();

    float creg[2][4] = {};   // c-state (waves 0-3; block owns its (b,j) slice)
    f32x4 acc00, acc01, acc10, acc11;
    ZACC();

    // prologue: cell0 x-part for t=0 (barrier-independent)
    if (cell == 0) {
        if (xb) KLOOP_BF16(xb + 0, (long)T_ * F_, 0);
        else    KLOOP_F32 (x  + 0, (long)T_ * F_, 0);
    }

    for (int p = 0; p <= T_; ++p) {
        if (cell == 0) {
            if (p < T_) {
                const int t = p;
                const __bf16* hprev = (t & 1) ? h0a : h0b;   // h0(t-1)
                __bf16* hw          = (t & 1) ? h0b : h0a;   // h0(t)
                KLOOP_BF16(hprev, H_, 1024);                 // acc already holds x-part(t)
                REDUCE_EPI(hw, t, false);
            }
        } else {
            if (p >= 1) {
                const int t = p - 1;
                ZACC();
                const __bf16* s0 = (t & 1) ? h0b : h0a;      // h0(t)
                const __bf16* s1 = (t & 1) ? h1a : h1b;      // h1(t-1)
                __bf16* hw       = (t & 1) ? h1b : h1a;      // h1(t)
                KLOOP_BF16(s0, H_, 0);
                KLOOP_BF16(s1, H_, 1024);
                REDUCE_EPI(hw, t, true);
            }
        }

        if (p < T_) {
            __syncthreads();           // all epilogue writes issued & drained
            unsigned g = 0;
            if (tid == 0) {
                __threadfence();       // release: wbl2 -> h/out visible at LLC
                g = __hip_atomic_load(gen, __ATOMIC_RELAXED, __HIP_MEMORY_SCOPE_AGENT);
                unsigned a = __hip_atomic_fetch_add(cnt, 1u, __ATOMIC_RELAXED,
                                                    __HIP_MEMORY_SCOPE_AGENT);
                if (a == 255u) {
                    __hip_atomic_store(cnt, 0u, __ATOMIC_RELAXED, __HIP_MEMORY_SCOPE_AGENT);
                    __hip_atomic_store(gen, g + 1u, __ATOMIC_RELEASE, __HIP_MEMORY_SCOPE_AGENT);
                }
            }
            // ---- barrier-hidden work: next timestep's x-projection (cell0) ----
            if (cell == 0) {
                ZACC();
                if (p + 1 < T_) {
                    if (xb) KLOOP_BF16(xb + (long)(p + 1) * F_, (long)T_ * F_, 0);
                    else    KLOOP_F32 (x  + (long)(p + 1) * F_, (long)T_ * F_, 0);
                }
            }
            if (tid == 0) {
                // relaxed poll (no per-poll buffer_inv); acquire-load fallback for safety
                for (;;) {
                    bool done = false;
                    for (int it = 0; it < 256; ++it) {
                        if (__hip_atomic_load(gen, __ATOMIC_RELAXED,
                                              __HIP_MEMORY_SCOPE_AGENT) != g) { done = true; break; }
                        __builtin_amdgcn_s_sleep(2);
                    }
                    if (done) break;
                    if (__hip_atomic_load(gen, __ATOMIC_ACQUIRE,
                                          __HIP_MEMORY_SCOPE_AGENT) != g) break;
                }
                __builtin_amdgcn_fence(__ATOMIC_ACQUIRE, "agent");  // single inv
            }
            __syncthreads();
        }
    }
}

extern "C" void kernel_launch(void* const* d_in, const int* in_sizes, int n_in,
                              void* d_out, int out_size, void* d_ws, size_t ws_size,
                              hipStream_t stream)
{
    const float* x    = (const float*)d_in[0];
    const float* Wih0 = (const float*)d_in[1];
    const float* bih0 = (const float*)d_in[2];
    const float* Whh0 = (const float*)d_in[3];
    const float* bhh0 = (const float*)d_in[4];
    const float* Wih1 = (const float*)d_in[5];
    const float* bih1 = (const float*)d_in[6];
    const float* Whh1 = (const float*)d_in[7];
    const float* bhh1 = (const float*)d_in[8];
    float* out = (float*)d_out;

    // ws layout: [bar 4K] [h0a 256K][h0b 256K][h1a 256K][h1b 256K] [xb 64M optional]
    char* ws = (char*)d_ws;
    unsigned* bar = (unsigned*)ws;
    __bf16* h0a = (__bf16*)(ws + 4096);
    __bf16* h0b = (__bf16*)(ws + 4096 + (256 << 10));
    __bf16* h1a = (__bf16*)(ws + 4096 + (512 << 10));
    __bf16* h1b = (__bf16*)(ws + 4096 + (768 << 10));
    const __bf16* xb = nullptr;

    const size_t XB_OFF = 4096 + (1 << 20);
    if (ws_size >= XB_OFF + ((size_t)64 << 20)) {
        __bf16* xbw = (__bf16*)(ws + XB_OFF);
        k_cvt<<<dim3(16384), dim3(256), 0, stream>>>(x, xbw, B_ * T_ * F_);
        xb = xbw;
    }
    k_init<<<dim3(512), dim3(256), 0, stream>>>(h0b, h1b, bar);

    void* args[] = {
        (void*)&x, (void*)&Wih0, (void*)&Whh0, (void*)&Wih1, (void*)&Whh1,
        (void*)&bih0, (void*)&bhh0, (void*)&bih1, (void*)&bhh1,
        (void*)&h0a, (void*)&h0b, (void*)&h1a, (void*)&h1b,
        (void*)&bar, (void*)&xb, (void*)&out
    };
    hipError_t err = hipLaunchCooperativeKernel((const void*)lstm_persist,
                                                dim3(256), dim3(512), args, 0, stream);
    if (err != hipSuccess) {
        // Fallback: 256 blocks at 1 block/CU are co-resident; the hand-rolled
        // barrier does not depend on cooperative-launch metadata.
        lstm_persist<<<dim3(256), dim3(512), 0, stream>>>(
            x, Wih0, Whh0, Wih1, Whh1, bih0, bhh0, bih1, bhh1,
            h0a, h0b, h1a, h1b, bar, xb, out);
    }
    (void)in_sizes; (void)n_in; (void)out_size;
}

// Round 4
// 6672.490 us; speedup vs baseline: 1.8492x; 1.1054x over previous
//
#include <hip/hip_runtime.h>

// Problem constants
#define B_ 128
#define T_ 256
#define F_ 1024
#define H_ 1024

typedef __bf16 bf16x8 __attribute__((ext_vector_type(8)));
typedef __bf16 bf16x4 __attribute__((ext_vector_type(4)));
typedef float f32x4 __attribute__((ext_vector_type(4)));

#define WROW 2056   // LDS weight row stride (bf16): 4112 B, 16B-aligned
#define XLDA 72     // k_xproj LDS row stride (bf16), +8 pad

__device__ __forceinline__ float sigf(float v)  { return 1.0f / (1.0f + __expf(-v)); }
// NaN-free tanh
__device__ __forceinline__ float tanhfast(float x) { return 1.0f - 2.0f / (1.0f + __expf(2.0f * x)); }

// fp32 -> bf16 (n must equal 8*256*gridDim)
__global__ void k_cvt(const float* __restrict__ src, __bf16* __restrict__ dst, int n) {
    int i = (blockIdx.x * 256 + threadIdx.x) * 8;
    if (i + 7 < n) {
        float4 a = *(const float4*)(src + i);
        float4 b = *(const float4*)(src + i + 4);
        bf16x8 o = { (__bf16)a.x, (__bf16)a.y, (__bf16)a.z, (__bf16)a.w,
                     (__bf16)b.x, (__bf16)b.y, (__bf16)b.z, (__bf16)b.w };
        *(bf16x8*)(dst + i) = o;
    }
}

// Zero the t=-1 h buffers and the barrier state (ws is poisoned).
__global__ void k_init(__bf16* h0b, __bf16* h1b, unsigned* bar) {
    int i = blockIdx.x * 256 + threadIdx.x;   // 512 x 256 = 131072 exactly
    h0b[i] = (__bf16)0.0f;
    h1b[i] = (__bf16)0.0f;
    if (i < 256) bar[i] = 0u;
}

// Precompute xproj = x . Wih0^T (NO bias) into packed per-recurrent-block tiles:
//   xp[t][cidx][b][n]  (n = gate*8 + jj, 32 per block)  -> tile of 128*32, 4096 elems.
// Grid 32768 = 256 t x (2 m-tiles x 64 n-tiles). Plain tiled GEMM, bf16 A (xb), fp32 B.
__global__ __launch_bounds__(256) void k_xproj(
    const __bf16* __restrict__ xb, const float* __restrict__ Wih0,
    float* __restrict__ xpf, __bf16* __restrict__ xpb)
{
    const int t   = blockIdx.x >> 7;
    const int sub = blockIdx.x & 127;
    const int m0  = (sub & 1) * 64;
    const int n0  = (sub >> 1) * 64;

    __shared__ __align__(16) __bf16 lsA[64 * XLDA];
    __shared__ __align__(16) __bf16 lsB[64 * XLDA];

    const int tid  = threadIdx.x;
    const int wave = tid >> 6;
    const int lane = tid & 63;
    const int quad = lane >> 4;
    const int lrow = lane & 15;

    f32x4 a0 = {0,0,0,0}, a1 = {0,0,0,0}, a2 = {0,0,0,0}, a3 = {0,0,0,0};

    for (int kt = 0; kt < 1024; kt += 64) {
        #pragma unroll
        for (int i = 0; i < 2; ++i) {            // A: 64 b-rows x 64 k (bf16)
            int idx = tid + i * 256;
            int r = idx >> 3, s = idx & 7;
            *(uint4*)&lsA[r * XLDA + s * 8] =
                *(const uint4*)(xb + ((long)(m0 + r) * T_ + t) * F_ + kt + s * 8);
        }
        #pragma unroll
        for (int i = 0; i < 4; ++i) {            // B: 64 gate-rows x 64 k (fp32 -> bf16)
            int idx = tid + i * 256;
            int r = idx >> 4, s = idx & 15;
            float4 v = *(const float4*)(Wih0 + (long)(n0 + r) * F_ + kt + s * 4);
            bf16x4 o = { (__bf16)v.x, (__bf16)v.y, (__bf16)v.z, (__bf16)v.w };
            *(bf16x4*)&lsB[r * XLDA + s * 4] = o;
        }
        __syncthreads();
        #pragma unroll
        for (int ki = 0; ki < 64; ki += 32) {
            bf16x8 af = *(const bf16x8*)&lsA[(wave * 16 + lrow) * XLDA + ki + quad * 8];
            bf16x8 b0 = *(const bf16x8*)&lsB[( 0 + lrow) * XLDA + ki + quad * 8];
            bf16x8 b1 = *(const bf16x8*)&lsB[(16 + lrow) * XLDA + ki + quad * 8];
            bf16x8 b2 = *(const bf16x8*)&lsB[(32 + lrow) * XLDA + ki + quad * 8];
            bf16x8 b3 = *(const bf16x8*)&lsB[(48 + lrow) * XLDA + ki + quad * 8];
            a0 = __builtin_amdgcn_mfma_f32_16x16x32_bf16(af, b0, a0, 0, 0, 0);
            a1 = __builtin_amdgcn_mfma_f32_16x16x32_bf16(af, b1, a1, 0, 0, 0);
            a2 = __builtin_amdgcn_mfma_f32_16x16x32_bf16(af, b2, a2, 0, 0, 0);
            a3 = __builtin_amdgcn_mfma_f32_16x16x32_bf16(af, b3, a3, 0, 0, 0);
        }
        __syncthreads();
    }

    const long xbase = (long)t * 524288;   // t*128*4096
    #define XSTORE(NT, ACC) { \
        int n = n0 + (NT) * 16 + lrow; int g = n >> 10; int jc = n & 1023; \
        long off = xbase + (long)(jc >> 3) * 4096 + (long)b * 32 + g * 8 + (jc & 7); \
        if (xpf) xpf[off] = (ACC)[r]; else xpb[off] = (__bf16)(ACC)[r]; }
    #pragma unroll
    for (int r = 0; r < 4; ++r) {
        const int b = m0 + wave * 16 + quad * 4 + r;
        XSTORE(0, a0) XSTORE(1, a1) XSTORE(2, a2) XSTORE(3, a3)
    }
    #undef XSTORE
}

// One K=32 slice for 2 M-tiles x 2 N-tiles; B from resident LDS weights.
#define STEP(A0, A1, KW) do { \
    bf16x8 b0_ = *(const bf16x8*)&wB[lrow][(KW) + quad * 8]; \
    bf16x8 b1_ = *(const bf16x8*)&wB[16 + lrow][(KW) + quad * 8]; \
    acc00 = __builtin_amdgcn_mfma_f32_16x16x32_bf16(A0, b0_, acc00, 0, 0, 0); \
    acc01 = __builtin_amdgcn_mfma_f32_16x16x32_bf16(A0, b1_, acc01, 0, 0, 0); \
    acc10 = __builtin_amdgcn_mfma_f32_16x16x32_bf16(A1, b0_, acc10, 0, 0, 0); \
    acc11 = __builtin_amdgcn_mfma_f32_16x16x32_bf16(A1, b1_, acc11, 0, 0, 0); \
} while (0)

// K-half loop over PACKED h (h[jblk][row][8]): lane's 16B = one (jblk,row) cell.
// Wave reads 4x256B contiguous segments per instruction. WBASE: LDS weight col base.
#define KLOOP_H(SRC, WBASE) do { \
    const __bf16* ph_ = (SRC) + ((long)((kbase >> 3) + quad)) * 1024 + arow0 * 8; \
    _Pragma("unroll") \
    for (int ks_ = 0; ks_ < 16; ++ks_) { \
        bf16x8 a0_ = *(const bf16x8*)(ph_ + ks_ * 4096); \
        bf16x8 a1_ = *(const bf16x8*)(ph_ + ks_ * 4096 + 128); \
        STEP(a0_, a1_, (WBASE) + kbase + ks_ * 32); \
    } \
} while (0)

// Row-major bf16 A (x fallback path), stride S.
#define KLOOP_RM(SRC, S, WBASE) do { \
    const __bf16* pa_ = (SRC) + (long)arow0 * (S) + kbase + quad * 8; \
    const __bf16* pb_ = (SRC) + (long)arow1 * (S) + kbase + quad * 8; \
    _Pragma("unroll") \
    for (int ks_ = 0; ks_ < 16; ++ks_) { \
        bf16x8 a0_ = *(const bf16x8*)(pa_ + ks_ * 32); \
        bf16x8 a1_ = *(const bf16x8*)(pb_ + ks_ * 32); \
        STEP(a0_, a1_, (WBASE) + kbase + ks_ * 32); \
    } \
} while (0)

// Row-major fp32 A with inline convert (x fallback when no xb).
#define KLOOP_F32(SRC, S, WBASE) do { \
    const float* pa_ = (SRC) + (long)arow0 * (S) + kbase + quad * 8; \
    const float* pb_ = (SRC) + (long)arow1 * (S) + kbase + quad * 8; \
    _Pragma("unroll") \
    for (int ks_ = 0; ks_ < 16; ++ks_) { \
        float4 va_ = *(const float4*)(pa_ + ks_ * 32); \
        float4 vb_ = *(const float4*)(pa_ + ks_ * 32 + 4); \
        float4 vc_ = *(const float4*)(pb_ + ks_ * 32); \
        float4 vd_ = *(const float4*)(pb_ + ks_ * 32 + 4); \
        bf16x8 a0_ = { (__bf16)va_.x, (__bf16)va_.y, (__bf16)va_.z, (__bf16)va_.w, \
                       (__bf16)vb_.x, (__bf16)vb_.y, (__bf16)vb_.z, (__bf16)vb_.w }; \
        bf16x8 a1_ = { (__bf16)vc_.x, (__bf16)vc_.y, (__bf16)vc_.z, (__bf16)vc_.w, \
                       (__bf16)vd_.x, (__bf16)vd_.y, (__bf16)vd_.z, (__bf16)vd_.w }; \
        STEP(a0_, a1_, (WBASE) + kbase + ks_ * 32); \
    } \
} while (0)

#define ZACC() do { \
    acc00 = (f32x4){0.f,0.f,0.f,0.f}; acc01 = (f32x4){0.f,0.f,0.f,0.f}; \
    acc10 = (f32x4){0.f,0.f,0.f,0.f}; acc11 = (f32x4){0.f,0.f,0.f,0.f}; \
} while (0)

// Add precomputed xproj tile (xp[b*32+n], b=wave*32+MT*16+quad*4+r, n=lrow/16+lrow).
#define XPADD(P) do { \
    _Pragma("unroll") \
    for (int r_ = 0; r_ < 4; ++r_) { \
        int b0_ = (wave << 5) + (quad << 2) + r_; \
        acc00[r_] += (float)(P)[b0_ * 32 + lrow]; \
        acc01[r_] += (float)(P)[b0_ * 32 + 16 + lrow]; \
        acc10[r_] += (float)(P)[(b0_ + 16) * 32 + lrow]; \
        acc11[r_] += (float)(P)[(b0_ + 16) * 32 + 16 + lrow]; \
    } \
} while (0)

// Epilogue for one M-tile (waves 0-3). h write is PACKED: HW pre-offset to this
// block's 2KB region; 8 low lanes write 16B contiguous per row.
#define EPI(MT, ACC_A, ACC_B, HW, TT, WOUT) \
    _Pragma("unroll") \
    for (int r = 0; r < 4; ++r) { \
        float v0 = (ACC_A)[r], v1 = (ACC_B)[r]; \
        float q0 = __shfl_xor(v0, 8); \
        float q1 = __shfl_xor(v1, 8); \
        float iv = (hi ? q0 : v0) + bi; \
        float fv = (hi ? v0 : q0) + bf_; \
        float gv = (hi ? q1 : v1) + bg; \
        float ov = (hi ? v1 : q1) + bo; \
        float cn = sigf(fv) * creg[MT][r] + sigf(iv) * tanhfast(gv); \
        creg[MT][r] = cn; \
        float hn = sigf(ov) * tanhfast(cn); \
        if (!hi) { \
            const int b = (wave << 5) + (MT) * 16 + (quad << 2) + r; \
            (HW)[b * 8 + jj] = (__bf16)hn; \
            if (WOUT) out[((long)b * T_ + (TT)) * H_ + j0 + jj] = hn; \
        } \
    }

// Split-K reduce (wave w+4 -> w), optional xproj add, epilogue.
#define REDUCE_EPI(HW, TT, WOUT, XOFF) do { \
    if (wave >= 4) { \
        _Pragma("unroll") \
        for (int i_ = 0; i_ < 4; ++i_) { \
            red[wave - 4][i_     ][lane] = acc00[i_]; \
            red[wave - 4][i_ + 4 ][lane] = acc01[i_]; \
            red[wave - 4][i_ + 8 ][lane] = acc10[i_]; \
            red[wave - 4][i_ + 12][lane] = acc11[i_]; \
        } \
    } \
    __syncthreads(); \
    if (wave < 4) { \
        _Pragma("unroll") \
        for (int i_ = 0; i_ < 4; ++i_) { \
            acc00[i_] += red[wave][i_     ][lane]; \
            acc01[i_] += red[wave][i_ + 4 ][lane]; \
            acc10[i_] += red[wave][i_ + 8 ][lane]; \
            acc11[i_] += red[wave][i_ + 12][lane]; \
        } \
        if ((XOFF) >= 0) { \
            if (xpf)      { const float*  xp_ = xpf + (XOFF); XPADD(xp_); } \
            else          { const __bf16* xp_ = xpb + (XOFF); XPADD(xp_); } \
        } \
        const float bi  = bb[jj]; \
        const float bf_ = bb[8 + jj]; \
        const float bg  = bb[16 + jj]; \
        const float bo  = bb[24 + jj]; \
        EPI(0, acc00, acc01, HW, TT, WOUT); \
        EPI(1, acc10, acc11, HW, TT, WOUT); \
    } \
} while (0)

// Persistent kernel: 256 blocks (1/CU), 512 threads (8 waves). Blocks [0,128)=cell0,
// [128,256)=cell1. Weights resident in LDS; split-K wave pairs; h buffers PACKED
// [cidx][row][8]; xproj precomputed (xpf/xpb) removes cell0's x-matmul.
// Tree barrier: 8 padded leaf counters -> root -> gen (monotonic, no resets).
__global__ __launch_bounds__(512, 1) void lstm_persist(
    const float* __restrict__ x,
    const float* __restrict__ Wih0, const float* __restrict__ Whh0,
    const float* __restrict__ Wih1, const float* __restrict__ Whh1,
    const float* __restrict__ bih0, const float* __restrict__ bhh0,
    const float* __restrict__ bih1, const float* __restrict__ bhh1,
    __bf16* __restrict__ h0a, __bf16* __restrict__ h0b,
    __bf16* __restrict__ h1a, __bf16* __restrict__ h1b,
    unsigned* bar, const __bf16* __restrict__ xb,
    const float* __restrict__ xpf, const __bf16* __restrict__ xpb,
    float* __restrict__ out)
{
    const int cell = blockIdx.x >> 7;
    const int cidx = blockIdx.x & 127;
    const int j0   = cidx << 3;            // 8 h-columns per block

    __shared__ __align__(16) __bf16 wB[32][WROW];   // 131,584 B resident weights
    __shared__ __align__(16) float  red[4][16][64]; // 16,384 B split-K partials
    __shared__ float bb[32];                        // bias sums

    const int tid  = threadIdx.x;
    const int wave = tid >> 6;             // 0..7
    const int lane = tid & 63;
    const int quad = lane >> 4;
    const int lrow = lane & 15;
    const int jj   = lane & 7;
    const bool hi  = (lane & 8) != 0;

    const int kbase = (wave >> 2) << 9;              // 0 or 512: K-half per wave
    const int arow0 = ((wave & 3) << 5) + lrow;      // M-tile pair shared by w, w+4
    const int arow1 = arow0 + 16;
    const bool hasxp = (xpf != nullptr) || (xpb != nullptr);

    const float* Wih = cell ? Wih1 : Wih0;
    const float* Whh = cell ? Whh1 : Whh0;

    // ---- one-time: stage 32 gate-rows x K=2048 weights into LDS ----
    for (int e = tid; e < 32 * 512; e += 512) {
        int n  = e >> 9;
        int k  = (e & 511) << 2;
        int wr = ((n >> 3) << 10) + j0 + (n & 7);
        const float* src = (k < 1024) ? (Wih + (long)wr * 1024 + k)
                                      : (Whh + (long)wr * 1024 + (k - 1024));
        float4 v = *(const float4*)src;
        bf16x4 o = { (__bf16)v.x, (__bf16)v.y, (__bf16)v.z, (__bf16)v.w };
        *(bf16x4*)&wB[n][k] = o;
    }
    if (tid < 32) {
        int wr = ((tid >> 3) << 10) + j0 + (tid & 7);
        bb[tid] = cell ? (bih1[wr] + bhh1[wr]) : (bih0[wr] + bhh0[wr]);
    }
    __syncthreads();

    float creg[2][4] = {};   // c-state (waves 0-3)
    f32x4 acc00, acc01, acc10, acc11;
    ZACC();

    // prologue (fallback only): cell0 x-part for t=0
    if (cell == 0 && !hasxp) {
        if (xb) KLOOP_RM(xb + 0, (long)T_ * F_, 0);
        else    KLOOP_F32(x + 0, (long)T_ * F_, 0);
    }

    for (int p = 0; p <= T_; ++p) {
        if (cell == 0) {
            if (p < T_) {
                const int t = p;
                const __bf16* hprev = (t & 1) ? h0a : h0b;            // h0(t-1), packed
                __bf16* hw = ((t & 1) ? h0b : h0a) + cidx * 1024;     // h0(t), own tile
                if (hasxp) ZACC();
                KLOOP_H(hprev, 1024);
                const long xoff = hasxp ? (((long)t * 128 + cidx) * 4096) : -1;
                REDUCE_EPI(hw, t, false, xoff);
            }
        } else {
            if (p >= 1) {
                const int t = p - 1;
                ZACC();
                const __bf16* s0 = (t & 1) ? h0b : h0a;               // h0(t)
                const __bf16* s1 = (t & 1) ? h1a : h1b;               // h1(t-1)
                __bf16* hw = ((t & 1) ? h1b : h1a) + cidx * 1024;     // h1(t)
                KLOOP_H(s0, 0);
                KLOOP_H(s1, 1024);
                REDUCE_EPI(hw, t, true, (long)-1);
            }
        }

        if (p < T_) {
            __syncthreads();                 // all epilogue stores drained (vmcnt 0)
            const unsigned genv = (unsigned)(p + 1);
            if (tid == 0) {
                __threadfence();             // release: L2 writeback to LLC
                unsigned v = __hip_atomic_fetch_add(&bar[(blockIdx.x & 7) << 4], 1u,
                                 __ATOMIC_RELAXED, __HIP_MEMORY_SCOPE_AGENT) + 1u;
                if (v == 32u * genv) {
                    unsigned r = __hip_atomic_fetch_add(&bar[128], 1u,
                                     __ATOMIC_RELAXED, __HIP_MEMORY_SCOPE_AGENT) + 1u;
                    if (r == 8u * genv)
                        __hip_atomic_store(&bar[136], genv,
                                           __ATOMIC_RELEASE, __HIP_MEMORY_SCOPE_AGENT);
                }
            }
            // fallback-only hidden work: next x-projection
            if (cell == 0 && !hasxp) {
                ZACC();
                if (p + 1 < T_) {
                    if (xb) KLOOP_RM(xb + (long)(p + 1) * F_, (long)T_ * F_, 0);
                    else    KLOOP_F32(x + (long)(p + 1) * F_, (long)T_ * F_, 0);
                }
            }
            if (tid == 0) {
                for (;;) {
                    bool done = false;
                    for (int it = 0; it < 128; ++it) {
                        if (__hip_atomic_load(&bar[136], __ATOMIC_RELAXED,
                                __HIP_MEMORY_SCOPE_AGENT) >= genv) { done = true; break; }
                        __builtin_amdgcn_s_sleep(1);
                    }
                    if (done) break;
                    if (__hip_atomic_load(&bar[136], __ATOMIC_ACQUIRE,
                            __HIP_MEMORY_SCOPE_AGENT) >= genv) break;
                }
                __builtin_amdgcn_fence(__ATOMIC_ACQUIRE, "agent");  // single inv
            }
            __syncthreads();
        }
    }
}

extern "C" void kernel_launch(void* const* d_in, const int* in_sizes, int n_in,
                              void* d_out, int out_size, void* d_ws, size_t ws_size,
                              hipStream_t stream)
{
    const float* x    = (const float*)d_in[0];
    const float* Wih0 = (const float*)d_in[1];
    const float* bih0 = (const float*)d_in[2];
    const float* Whh0 = (const float*)d_in[3];
    const float* bhh0 = (const float*)d_in[4];
    const float* Wih1 = (const float*)d_in[5];
    const float* bih1 = (const float*)d_in[6];
    const float* Whh1 = (const float*)d_in[7];
    const float* bhh1 = (const float*)d_in[8];
    float* out = (float*)d_out;

    // ws: [bar 4K][h0a 256K][h0b 256K][h1a 256K][h1b 256K][xb 64M][xp 256M/512M]
    char* ws = (char*)d_ws;
    unsigned* bar = (unsigned*)ws;
    __bf16* h0a = (__bf16*)(ws + 4096);
    __bf16* h0b = (__bf16*)(ws + 4096 + (256 << 10));
    __bf16* h1a = (__bf16*)(ws + 4096 + (512 << 10));
    __bf16* h1b = (__bf16*)(ws + 4096 + (768 << 10));

    const size_t XB_OFF = 4096 + (1 << 20);
    const size_t XP_OFF = XB_OFF + ((size_t)64 << 20);
    const __bf16* xb  = nullptr;
    float*  xpf = nullptr;
    __bf16* xpb = nullptr;

    if (ws_size >= XP_OFF) {                          // room for xb
        __bf16* xbw = (__bf16*)(ws + XB_OFF);
        k_cvt<<<dim3(16384), dim3(256), 0, stream>>>(x, xbw, B_ * T_ * F_);
        xb = xbw;
        if (ws_size >= XP_OFF + ((size_t)512 << 20))       xpf = (float*)(ws + XP_OFF);
        else if (ws_size >= XP_OFF + ((size_t)256 << 20))  xpb = (__bf16*)(ws + XP_OFF);
        if (xpf || xpb)
            k_xproj<<<dim3(32768), dim3(256), 0, stream>>>(xb, Wih0, xpf, xpb);
    }
    k_init<<<dim3(512), dim3(256), 0, stream>>>(h0b, h1b, bar);

    const float* xpf_c = xpf; const __bf16* xpb_c = xpb;
    void* args[] = {
        (void*)&x, (void*)&Wih0, (void*)&Whh0, (void*)&Wih1, (void*)&Whh1,
        (void*)&bih0, (void*)&bhh0, (void*)&bih1, (void*)&bhh1,
        (void*)&h0a, (void*)&h0b, (void*)&h1a, (void*)&h1b,
        (void*)&bar, (void*)&xb, (void*)&xpf_c, (void*)&xpb_c, (void*)&out
    };
    hipError_t err = hipLaunchCooperativeKernel((const void*)lstm_persist,
                                                dim3(256), dim3(512), args, 0, stream);
    if (err != hipSuccess) {
        lstm_persist<<<dim3(256), dim3(512), 0, stream>>>(
            x, Wih0, Whh0, Wih1, Whh1, bih0, bhh0, bih1, bhh1,
            h0a, h0b, h1a, h1b, bar, xb, xpf_c, xpb_c, out);
    }
    (void)in_sizes; (void)n_in; (void)out_size;
}

// Round 5
// 5981.530 us; speedup vs baseline: 2.0628x; 1.1155x over previous
//
#include <hip/hip_runtime.h>

// Problem constants
#define B_ 128
#define T_ 256
#define F_ 1024
#define H_ 1024

typedef __bf16 bf16x8 __attribute__((ext_vector_type(8)));
typedef __bf16 bf16x4 __attribute__((ext_vector_type(4)));
typedef float f32x4 __attribute__((ext_vector_type(4)));

#define WROW 2056        // LDS weight row stride (bf16): 4112 B, 16B-aligned
#define HSLOT 131072L    // elems per h slot (128 rows x 128 jblk x 8)

__device__ __forceinline__ float sigf(float v)  { return 1.0f / (1.0f + __expf(-v)); }
// NaN-free tanh
__device__ __forceinline__ float tanhfast(float x) { return 1.0f - 2.0f / (1.0f + __expf(2.0f * x)); }

// fp32 -> bf16 (n must equal 8*256*gridDim)
__global__ void k_cvt(const float* __restrict__ src, __bf16* __restrict__ dst, int n) {
    int i = (blockIdx.x * 256 + threadIdx.x) * 8;
    if (i + 7 < n) {
        float4 a = *(const float4*)(src + i);
        float4 b = *(const float4*)(src + i + 4);
        bf16x8 o = { (__bf16)a.x, (__bf16)a.y, (__bf16)a.z, (__bf16)a.w,
                     (__bf16)b.x, (__bf16)b.y, (__bf16)b.z, (__bf16)b.w };
        *(bf16x8*)(dst + i) = o;
    }
}

// Zero the t=-1 h slots (slot 0 of each array) and the barrier state (ws poisoned).
__global__ void k_init(__bf16* h0s, __bf16* h1s, unsigned* bar) {
    int i = blockIdx.x * 256 + threadIdx.x;   // 512 x 256 = 131072 exactly
    h0s[i] = (__bf16)0.0f;
    h1s[i] = (__bf16)0.0f;
    if (i < 512) bar[i] = 0u;
}

// Relaxed agent-scope poll until *P >= V. No acquire fence: per-timestep buffers
// are single-version (never cached before their write), so L2 cannot be stale.
// The asm is a compiler-order barrier so subsequent loads aren't hoisted.
#define WAITGE(P, V) do { \
    while (__hip_atomic_load((P), __ATOMIC_RELAXED, __HIP_MEMORY_SCOPE_AGENT) < (V)) \
        __builtin_amdgcn_s_sleep(1); \
    asm volatile("" ::: "memory"); \
} while (0)

// small-ws fallback only: slot reuse makes stale L2 possible -> invalidate.
#define ACQ() __builtin_amdgcn_fence(__ATOMIC_ACQUIRE, "agent")

// One K=32 slice for 2 M-tiles x 2 N-tiles; B from resident LDS weights.
#define STEP(A0, A1, KW) do { \
    bf16x8 b0_ = *(const bf16x8*)&wB[lrow][(KW) + quad * 8]; \
    bf16x8 b1_ = *(const bf16x8*)&wB[16 + lrow][(KW) + quad * 8]; \
    acc00 = __builtin_amdgcn_mfma_f32_16x16x32_bf16(A0, b0_, acc00, 0, 0, 0); \
    acc01 = __builtin_amdgcn_mfma_f32_16x16x32_bf16(A0, b1_, acc01, 0, 0, 0); \
    acc10 = __builtin_amdgcn_mfma_f32_16x16x32_bf16(A1, b0_, acc10, 0, 0, 0); \
    acc11 = __builtin_amdgcn_mfma_f32_16x16x32_bf16(A1, b1_, acc11, 0, 0, 0); \
} while (0)

// Full-K (1024) loop over PACKED h (h[jblk][row][8]); wave reads 4x256B
// contiguous segments per instruction. WBASE: LDS weight column base.
#define KLOOP_HF(SRC, WBASE) do { \
    const __bf16* ph_ = (SRC) + (long)quad * 1024 + arow0 * 8; \
    _Pragma("unroll") \
    for (int ks_ = 0; ks_ < 32; ++ks_) { \
        bf16x8 a0_ = *(const bf16x8*)(ph_ + (long)ks_ * 4096); \
        bf16x8 a1_ = *(const bf16x8*)(ph_ + (long)ks_ * 4096 + 128); \
        STEP(a0_, a1_, (WBASE) + ks_ * 32); \
    } \
} while (0)

// Full-K row-major bf16 A (xb path), row stride S.
#define KLOOP_RMF(SRC, S, WBASE) do { \
    const __bf16* pa_ = (SRC) + (long)arow0 * (S) + quad * 8; \
    const __bf16* pb_ = (SRC) + (long)arow1 * (S) + quad * 8; \
    _Pragma("unroll") \
    for (int ks_ = 0; ks_ < 32; ++ks_) { \
        bf16x8 a0_ = *(const bf16x8*)(pa_ + ks_ * 32); \
        bf16x8 a1_ = *(const bf16x8*)(pb_ + ks_ * 32); \
        STEP(a0_, a1_, (WBASE) + ks_ * 32); \
    } \
} while (0)

// Full-K row-major fp32 A with inline convert (x fallback when no xb).
#define KLOOP_F32F(SRC, S, WBASE) do { \
    const float* pa_ = (SRC) + (long)arow0 * (S) + quad * 8; \
    const float* pb_ = (SRC) + (long)arow1 * (S) + quad * 8; \
    _Pragma("unroll") \
    for (int ks_ = 0; ks_ < 32; ++ks_) { \
        float4 va_ = *(const float4*)(pa_ + ks_ * 32); \
        float4 vb_ = *(const float4*)(pa_ + ks_ * 32 + 4); \
        float4 vc_ = *(const float4*)(pb_ + ks_ * 32); \
        float4 vd_ = *(const float4*)(pb_ + ks_ * 32 + 4); \
        bf16x8 a0_ = { (__bf16)va_.x, (__bf16)va_.y, (__bf16)va_.z, (__bf16)va_.w, \
                       (__bf16)vb_.x, (__bf16)vb_.y, (__bf16)vb_.z, (__bf16)vb_.w }; \
        bf16x8 a1_ = { (__bf16)vc_.x, (__bf16)vc_.y, (__bf16)vc_.z, (__bf16)vc_.w, \
                       (__bf16)vd_.x, (__bf16)vd_.y, (__bf16)vd_.z, (__bf16)vd_.w }; \
        STEP(a0_, a1_, (WBASE) + ks_ * 32); \
    } \
} while (0)

#define ZACC() do { \
    acc00 = (f32x4){0.f,0.f,0.f,0.f}; acc01 = (f32x4){0.f,0.f,0.f,0.f}; \
    acc10 = (f32x4){0.f,0.f,0.f,0.f}; acc11 = (f32x4){0.f,0.f,0.f,0.f}; \
} while (0)

// Epilogue for one M-tile (waves 0-3). PACKED h write (HW pre-offset to this
// block's 2KB tile); lanes jj / jj+8 hold (i,g)/(f,o); shfl_xor(8) reunites.
#define EPI(MT, ACC_A, ACC_B, HW, TT, WOUT) \
    _Pragma("unroll") \
    for (int r = 0; r < 4; ++r) { \
        float v0 = (ACC_A)[r], v1 = (ACC_B)[r]; \
        float q0 = __shfl_xor(v0, 8); \
        float q1 = __shfl_xor(v1, 8); \
        float iv = (hi ? q0 : v0) + bi; \
        float fv = (hi ? v0 : q0) + bf_; \
        float gv = (hi ? q1 : v1) + bg; \
        float ov = (hi ? v1 : q1) + bo; \
        float cn = sigf(fv) * creg[MT][r] + sigf(iv) * tanhfast(gv); \
        creg[MT][r] = cn; \
        float hn = sigf(ov) * tanhfast(cn); \
        if (!hi) { \
            const int b = (wave << 5) + (MT) * 16 + (quad << 2) + r; \
            (HW)[b * 8 + jj] = (__bf16)hn; \
            if (WOUT) out[((long)b * T_ + (TT)) * H_ + j0 + jj] = hn; \
        } \
    }

// Cross-wave matmul-part reduce (wave w+4 -> wave w), then epilogue (waves 0-3).
#define REDUCE_EPI(HW, TT, WOUT) do { \
    if (wave >= 4) { \
        _Pragma("unroll") \
        for (int i_ = 0; i_ < 4; ++i_) { \
            red[wave - 4][i_     ][lane] = acc00[i_]; \
            red[wave - 4][i_ + 4 ][lane] = acc01[i_]; \
            red[wave - 4][i_ + 8 ][lane] = acc10[i_]; \
            red[wave - 4][i_ + 12][lane] = acc11[i_]; \
        } \
    } \
    __syncthreads(); \
    if (wave < 4) { \
        _Pragma("unroll") \
        for (int i_ = 0; i_ < 4; ++i_) { \
            acc00[i_] += red[wave][i_     ][lane]; \
            acc01[i_] += red[wave][i_ + 4 ][lane]; \
            acc10[i_] += red[wave][i_ + 8 ][lane]; \
            acc11[i_] += red[wave][i_ + 12][lane]; \
        } \
        const float bi  = bb[jj]; \
        const float bf_ = bb[8 + jj]; \
        const float bg  = bb[16 + jj]; \
        const float bo  = bb[24 + jj]; \
        EPI(0, acc00, acc01, HW, TT, WOUT); \
        EPI(1, acc10, acc11, HW, TT, WOUT); \
    } \
} while (0)

// Persistent kernel: 256 blocks (1/CU), 512 threads. Blocks [0,128)=cell0,
// [128,256)=cell1; weights resident in LDS. h state is PER-TIMESTEP slotted
// (single-version -> no L2 invalidation, h L2-cacheable). Two independent
// 128-block group barriers (tree, monotonic); cell0 runs ahead of cell1.
// Within a block: waves 0-3 compute the input-side matmul, waves 4-7 the
// recurrent-side matmul (only the waves that NEED a gen wait on it).
__global__ __launch_bounds__(512, 1) void lstm_persist(
    const float* __restrict__ x,
    const float* __restrict__ Wih0, const float* __restrict__ Whh0,
    const float* __restrict__ Wih1, const float* __restrict__ Whh1,
    const float* __restrict__ bih0, const float* __restrict__ bhh0,
    const float* __restrict__ bih1, const float* __restrict__ bhh1,
    __bf16* __restrict__ h0s, __bf16* __restrict__ h1s,
    unsigned* bar, const __bf16* __restrict__ xb,
    float* __restrict__ out, int big)
{
    const int cell = blockIdx.x >> 7;
    const int cidx = blockIdx.x & 127;
    const int j0   = cidx << 3;            // 8 h-columns per block

    __shared__ __align__(16) __bf16 wB[32][WROW];   // 131,584 B resident weights
    __shared__ __align__(16) float  red[4][16][64]; // 16,384 B partials
    __shared__ float bb[32];                        // bias sums

    const int tid  = threadIdx.x;
    const int wave = tid >> 6;             // 0..7
    const int lane = tid & 63;
    const int quad = lane >> 4;
    const int lrow = lane & 15;
    const int jj   = lane & 7;
    const bool hi  = (lane & 8) != 0;

    const int arow0 = ((wave & 3) << 5) + lrow;   // M-rows shared by wave w and w+4
    const int arow1 = arow0 + 16;

    unsigned* leaf = bar + (cell ? 160 : 0) + ((cidx & 7) << 4);  // 8 leaves x 16
    unsigned* root = bar + (cell ? 288 : 128);
    unsigned* genA = bar + 144;            // cell0 completed phases
    unsigned* genB = bar + 304;            // cell1 completed phases
    unsigned* genMy = cell ? genB : genA;

    const float* Wih = cell ? Wih1 : Wih0;
    const float* Whh = cell ? Whh1 : Whh0;

    // ---- one-time: stage 32 gate-rows x K=2048 weights into LDS ----
    for (int e = tid; e < 32 * 512; e += 512) {
        int n  = e >> 9;
        int k  = (e & 511) << 2;
        int wr = ((n >> 3) << 10) + j0 + (n & 7);
        const float* src = (k < 1024) ? (Wih + (long)wr * 1024 + k)
                                      : (Whh + (long)wr * 1024 + (k - 1024));
        float4 v = *(const float4*)src;
        bf16x4 o = { (__bf16)v.x, (__bf16)v.y, (__bf16)v.z, (__bf16)v.w };
        *(bf16x4*)&wB[n][k] = o;
    }
    if (tid < 32) {
        int wr = ((tid >> 3) << 10) + j0 + (tid & 7);
        bb[tid] = cell ? (bih1[wr] + bhh1[wr]) : (bih0[wr] + bhh0[wr]);
    }
    __syncthreads();

    float creg[2][4] = {};   // c-state (waves 0-3)
    f32x4 acc00, acc01, acc10, acc11;

    for (int t = 0; t < T_; ++t) {
        const long sprev = big ? (long)t : (long)(t & 3);           // slot(t-1)
        const long scur  = big ? (long)(t + 1) : (long)((t + 1) & 3); // slot(t)
        ZACC();

        // small-ws mode: cell0 must not overwrite a slot cell1 still reads
        if (!big && cell == 0 && t >= 3) WAITGE(genB, (unsigned)(t - 3));

        if (cell == 0) {
            if (wave < 4) {
                // x-projection: depends on nothing -> no wait
                if (xb) KLOOP_RMF(xb + (long)t * F_, (long)T_ * F_, 0);
                else    KLOOP_F32F(x + (long)t * F_, (long)T_ * F_, 0);
            } else {
                WAITGE(genA, (unsigned)t);            // h0(t-1) ready
                if (!big) ACQ();
                KLOOP_HF(h0s + sprev * HSLOT, 1024);
            }
        } else {
            if (wave < 4) {
                WAITGE(genA, (unsigned)(t + 1));      // h0(t) ready
                if (!big) ACQ();
                KLOOP_HF(h0s + scur * HSLOT, 0);
            } else {
                WAITGE(genB, (unsigned)t);            // h1(t-1) ready
                if (!big) ACQ();
                KLOOP_HF(h1s + sprev * HSLOT, 1024);
            }
        }

        __bf16* hw = (cell ? h1s : h0s) + scur * HSLOT + (long)cidx * 1024;
        REDUCE_EPI(hw, t, cell != 0);

        __syncthreads();                   // all waves' stores acked in L2
        if (tid == 0) {
            __threadfence();               // release: dirty L2 -> LLC
            unsigned v = __hip_atomic_fetch_add(leaf, 1u, __ATOMIC_RELAXED,
                                                __HIP_MEMORY_SCOPE_AGENT) + 1u;
            if (v == 16u * (unsigned)(t + 1)) {
                unsigned r = __hip_atomic_fetch_add(root, 1u, __ATOMIC_RELAXED,
                                                    __HIP_MEMORY_SCOPE_AGENT) + 1u;
                if (r == 8u * (unsigned)(t + 1))
                    __hip_atomic_store(genMy, (unsigned)(t + 1),
                                       __ATOMIC_RELEASE, __HIP_MEMORY_SCOPE_AGENT);
            }
        }
        // no trailing syncthreads: next phase's waves poll gens independently
    }
}

extern "C" void kernel_launch(void* const* d_in, const int* in_sizes, int n_in,
                              void* d_out, int out_size, void* d_ws, size_t ws_size,
                              hipStream_t stream)
{
    const float* x    = (const float*)d_in[0];
    const float* Wih0 = (const float*)d_in[1];
    const float* bih0 = (const float*)d_in[2];
    const float* Whh0 = (const float*)d_in[3];
    const float* bhh0 = (const float*)d_in[4];
    const float* Wih1 = (const float*)d_in[5];
    const float* bih1 = (const float*)d_in[6];
    const float* Whh1 = (const float*)d_in[7];
    const float* bhh1 = (const float*)d_in[8];
    float* out = (float*)d_out;

    // ws: [bar 4K][h0 slots][h1 slots][xb 64M optional]
    // big: 257 slots x 256KB per cell (single-version h, no L2 invalidation)
    const size_t SLOT_B = 262144;
    char* ws = (char*)d_ws;
    unsigned* bar = (unsigned*)ws;

    const size_t bigNeed = 4096 + 2 * 257 * SLOT_B + ((size_t)64 << 20);
    const int big = (ws_size >= bigNeed) ? 1 : 0;
    const size_t nslot = big ? 257 : 4;

    __bf16* h0s = (__bf16*)(ws + 4096);
    __bf16* h1s = (__bf16*)(ws + 4096 + nslot * SLOT_B);
    const size_t xb_off = 4096 + 2 * nslot * SLOT_B;
    const __bf16* xb = nullptr;

    if (ws_size >= xb_off + ((size_t)64 << 20)) {
        __bf16* xbw = (__bf16*)(ws + xb_off);
        k_cvt<<<dim3(16384), dim3(256), 0, stream>>>(x, xbw, B_ * T_ * F_);
        xb = xbw;
    }
    k_init<<<dim3(512), dim3(256), 0, stream>>>(h0s, h1s, bar);

    int bigv = big;
    void* args[] = {
        (void*)&x, (void*)&Wih0, (void*)&Whh0, (void*)&Wih1, (void*)&Whh1,
        (void*)&bih0, (void*)&bhh0, (void*)&bih1, (void*)&bhh1,
        (void*)&h0s, (void*)&h1s, (void*)&bar, (void*)&xb, (void*)&out,
        (void*)&bigv
    };
    hipError_t err = hipLaunchCooperativeKernel((const void*)lstm_persist,
                                                dim3(256), dim3(512), args, 0, stream);
    if (err != hipSuccess) {
        // 256 blocks at 1 block/CU are co-resident; the hand-rolled barriers
        // do not depend on cooperative-launch metadata.
        lstm_persist<<<dim3(256), dim3(512), 0, stream>>>(
            x, Wih0, Whh0, Wih1, Whh1, bih0, bhh0, bih1, bhh1,
            h0s, h1s, bar, xb, out, bigv);
    }
    (void)in_sizes; (void)n_in; (void)out_size;
}